// Round 1
// baseline (197.488 us; speedup 1.0000x reference)
//
#include <hip/hip_runtime.h>

// KANLayer: out[b,s,o] = sum_i x*Wb + sum_{i,k} basis(x)_{ik} * Ws[o,i,k]
// Knots: [-1,-1,-1,-1,-0.6,-0.2,0.2,0.6,1,1,1,1] -> duplicate knots folded:
// 6 distinct hat functions + identity plane => GEMM with K = 1024*7 = 7168.
//
// C[M=8192][N=1024] = A[M][K] * Bt[N][K]^T   (bf16 inputs, f32 accumulate)

#define IN_F   1024
#define OUT_F  1024
#define NPLANE 7
#define K_DIM  (IN_F * NPLANE)   // 7168
#define M_DIM  8192
#define N_DIM  OUT_F

typedef __attribute__((ext_vector_type(8))) __bf16 bf16x8;
typedef __attribute__((ext_vector_type(4))) float f32x4;
typedef __attribute__((ext_vector_type(4))) unsigned short ushort4v;

__device__ inline unsigned short f2bf(float f) {
    union { float f; unsigned int u; } v; v.f = f;
    unsigned int u = v.u;
    unsigned int r = (u + 0x7FFFu + ((u >> 16) & 1u)) >> 16;  // RNE
    return (unsigned short)r;
}

// ---------------------------------------------------------------------------
// Fold weights -> Bt[N][K] bf16 (B^T layout: n-major, k contiguous).
// k = plane*1024 + i ; plane 0 = base_weight, 1 = sum(knots 0..3), 2..5 =
// knots 4..7, 6 = sum(knots 8..11).
// ---------------------------------------------------------------------------
__global__ void fold_w(const float* __restrict__ sw, const float* __restrict__ bw,
                       unsigned short* __restrict__ Bt) {
    int idx = blockIdx.x * 256 + threadIdx.x;       // o*1024 + i
    int o = idx >> 10, i = idx & 1023;
    const float4* p = reinterpret_cast<const float4*>(sw + (size_t)idx * 12);
    float4 a = p[0];   // knots 0..3  (all -1)
    float4 b = p[1];   // knots 4..7  (-0.6,-0.2,0.2,0.6)
    float4 c = p[2];   // knots 8..11 (all +1)
    size_t base = (size_t)o * K_DIM + i;
    Bt[base         ] = f2bf(bw[idx]);
    Bt[base + 1*1024] = f2bf(a.x + a.y + a.z + a.w);
    Bt[base + 2*1024] = f2bf(b.x);
    Bt[base + 3*1024] = f2bf(b.y);
    Bt[base + 4*1024] = f2bf(b.z);
    Bt[base + 5*1024] = f2bf(b.w);
    Bt[base + 6*1024] = f2bf(c.x + c.y + c.z + c.w);
}

// ---------------------------------------------------------------------------
// Expand x -> A[M][K] bf16. Plane 0 = x; planes 1..6 = hat_j(clip(x)),
// hat_j(t) = relu(1 - 2.5*|t - (-1+0.4j)|).
// One thread handles 4 consecutive i (float4 load, 8B stores per plane).
// ---------------------------------------------------------------------------
__global__ void expand_x(const float* __restrict__ x, unsigned short* __restrict__ Ax) {
    int idx = blockIdx.x * 256 + threadIdx.x;       // m*256 + i4
    int m = idx >> 8, i4 = idx & 255;
    float4 v = reinterpret_cast<const float4*>(x)[idx];
    float vv[4] = {v.x, v.y, v.z, v.w};
    size_t base = (size_t)m * K_DIM + i4 * 4;

    ushort4v s;
    #pragma unroll
    for (int e = 0; e < 4; ++e) s[e] = f2bf(vv[e]);
    *reinterpret_cast<ushort4v*>(Ax + base) = s;

    float xc[4];
    #pragma unroll
    for (int e = 0; e < 4; ++e) xc[e] = fminf(fmaxf(vv[e], -1.0f), 1.0f);

    #pragma unroll
    for (int j = 0; j < 6; ++j) {
        float t = -1.0f + 0.4f * (float)j;
        #pragma unroll
        for (int e = 0; e < 4; ++e) {
            float h = fmaxf(1.0f - fabsf((xc[e] - t) * 2.5f), 0.0f);
            s[e] = f2bf(h);
        }
        *reinterpret_cast<ushort4v*>(Ax + base + (size_t)(j + 1) * 1024) = s;
    }
}

// ---------------------------------------------------------------------------
// GEMM: C[M][N] = A[M][K] * Bt[N][K]^T, m97 structure:
// 128x128 tile, BK=64, 4 waves (2x2, each 64x64), 16x16x32 bf16 MFMA,
// global_load_lds width-16 staging, linear LDS, 2 barriers per K-step.
// ---------------------------------------------------------------------------
__global__ __launch_bounds__(256) void gemm_bt(
        const unsigned short* __restrict__ A,   // [M][K] bf16
        const unsigned short* __restrict__ B,   // [N][K] bf16
        float* __restrict__ C) {                // [M][N] f32
    __shared__ unsigned short As[128 * 64];
    __shared__ unsigned short Bs[128 * 64];

    const int t    = threadIdx.x;
    const int wave = t >> 6;
    const int lane = t & 63;
    const int wr   = wave >> 1;      // wave row (0..1)
    const int wc   = wave & 1;       // wave col (0..1)
    const int bx   = blockIdx.x;     // N tile (0..7)
    const int by   = blockIdx.y;     // M tile (0..63)

    // staging: thread t loads 16B: tile row = i*32 + t/8, k-offset = (t%8)*8
    const int srow = t >> 3;
    const int skp  = (t & 7) * 8;
    const size_t a_src = (size_t)(by * 128 + srow) * K_DIM + skp;
    const size_t b_src = (size_t)(bx * 128 + srow) * K_DIM + skp;
    unsigned short* As_dst = As + wave * 512;   // wave-uniform; HW adds lane*16B
    unsigned short* Bs_dst = Bs + wave * 512;

    f32x4 acc[4][4];
    const f32x4 zero = {0.f, 0.f, 0.f, 0.f};
    #pragma unroll
    for (int m = 0; m < 4; ++m)
        #pragma unroll
        for (int n = 0; n < 4; ++n) acc[m][n] = zero;

    // fragment read bases (element offsets in LDS): row = (lane&15), k = (lane>>4)*8
    const int ar = (wr * 64 + (lane & 15)) * 64 + (lane >> 4) * 8;
    const int br = (wc * 64 + (lane & 15)) * 64 + (lane >> 4) * 8;

    for (int kt = 0; kt < K_DIM; kt += 64) {
        #pragma unroll
        for (int i = 0; i < 4; ++i) {
            __builtin_amdgcn_global_load_lds(
                (const __attribute__((address_space(1))) void*)(A + a_src + (size_t)i * 32 * K_DIM + kt),
                (__attribute__((address_space(3))) void*)(As_dst + i * 2048), 16, 0, 0);
            __builtin_amdgcn_global_load_lds(
                (const __attribute__((address_space(1))) void*)(B + b_src + (size_t)i * 32 * K_DIM + kt),
                (__attribute__((address_space(3))) void*)(Bs_dst + i * 2048), 16, 0, 0);
        }
        __syncthreads();   // compiler emits s_waitcnt vmcnt(0) before s_barrier

        #pragma unroll
        for (int kk = 0; kk < 2; ++kk) {
            bf16x8 af[4], bf[4];
            #pragma unroll
            for (int m = 0; m < 4; ++m)
                af[m] = *reinterpret_cast<const bf16x8*>(As + ar + m * 16 * 64 + kk * 32);
            #pragma unroll
            for (int n = 0; n < 4; ++n)
                bf[n] = *reinterpret_cast<const bf16x8*>(Bs + br + n * 16 * 64 + kk * 32);
            #pragma unroll
            for (int m = 0; m < 4; ++m)
                #pragma unroll
                for (int n = 0; n < 4; ++n)
                    acc[m][n] = __builtin_amdgcn_mfma_f32_16x16x32_bf16(af[m], bf[n], acc[m][n], 0, 0, 0);
        }
        __syncthreads();
    }

    // C/D layout (verified m89/m91): col = lane&15, row = (lane>>4)*4 + reg
    const int crow = by * 128 + wr * 64 + ((lane >> 4) << 2);
    const int ccol = bx * 128 + wc * 64 + (lane & 15);
    #pragma unroll
    for (int m = 0; m < 4; ++m)
        #pragma unroll
        for (int n = 0; n < 4; ++n)
            #pragma unroll
            for (int r = 0; r < 4; ++r)
                C[(size_t)(crow + m * 16 + r) * N_DIM + ccol + n * 16] = acc[m][n][r];
}

// ---------------------------------------------------------------------------
extern "C" void kernel_launch(void* const* d_in, const int* in_sizes, int n_in,
                              void* d_out, int out_size, void* d_ws, size_t ws_size,
                              hipStream_t stream) {
    const float* x  = (const float*)d_in[0];   // (4,2048,1024) f32
    const float* sw = (const float*)d_in[1];   // (1024,1024,12) f32
    const float* bw = (const float*)d_in[2];   // (1024,1024) f32
    float* out = (float*)d_out;                // (4,2048,1024) f32

    // workspace: Aexp = M*K bf16 (117,440,512 B), Bt = N*K bf16 (14,680,064 B)
    unsigned short* Ax = (unsigned short*)d_ws;
    unsigned short* Bt = (unsigned short*)((char*)d_ws + (size_t)M_DIM * K_DIM * 2);

    fold_w<<<(OUT_F * IN_F) / 256, 256, 0, stream>>>(sw, bw, Bt);
    expand_x<<<(M_DIM * IN_F / 4) / 256, 256, 0, stream>>>(x, Ax);

    dim3 grid(N_DIM / 128, M_DIM / 128);
    gemm_bt<<<grid, 256, 0, stream>>>(Ax, Bt, out);
}